// Round 8
// baseline (476.945 us; speedup 1.0000x reference)
//
#include <hip/hip_runtime.h>

// LSTM_61203283968689 — R8 (= R7 + compile fix): MFMA fused 3-layer LSTM,
// deep diagonal + cross-tick software pipelining.
// 256 blocks x 768 threads (12 waves, 3/SIMD):
// waves 0-3 -> L0 (time t at tick t), 4-7 -> L1 (time t-2), 8-11 -> L2 (time t-4).
// Each wave splits its gate matmul into TIGHT self-h MFMAs (recurrence-critical,
// 2 per gate chain) and SLACK cross MFMAs (x / previous-layer h, >=1 tick of slack)
// which compute zc_next for the NEXT tick and execute under this tick's ew VALU
// chain -> MFMA pipe (~755 cy/SIMD/tick) and VALU (~720 cy) overlap instead of
// serializing (R6: 1730 cy/tick = 755+720+stall).
// h ring buffers: 4 slots per layer, slot = time & 3. ONE barrier per tick.
// Wave wg owns gates {i,f,g,o} of units [16wg,16wg+16); 4 samples on C-rows
// {0,4,8,12} (reg 0 of each kg). Fragment-linear LDS, lane reads at lane*16B.

#define TT   512
#define NTH  768
#define NBLK 256

typedef _Float16 h16;
typedef __attribute__((ext_vector_type(8))) _Float16 h16x8;
typedef __attribute__((ext_vector_type(4))) float f32x4;

#define MFMA16(a, b, c) __builtin_amdgcn_mfma_f32_16x16x32_f16((a), (b), (c), 0, 0, 0)

__device__ __forceinline__ float sigm(float z) {
    return __builtin_amdgcn_rcpf(1.f + __expf(-z));
}

// B-fragment: 8 consecutive k of row `ro` from row-major W[.,ld], f32 -> f16.
__device__ __forceinline__ h16x8 loadB(const float* __restrict__ W, int ld, int ro,
                                       int k0, int kmax) {
    h16x8 r;
    #pragma unroll
    for (int i = 0; i < 8; ++i) {
        const int k = k0 + i;
        r[i] = (h16)((k < kmax) ? W[(size_t)ro * ld + k] : 0.f);
    }
    return r;
}

__global__ __attribute__((amdgpu_flat_work_group_size(NTH, NTH), amdgpu_waves_per_eu(3)))
void lstm_mfma(
    const float* __restrict__ x,
    const float* __restrict__ wih0, const float* __restrict__ whh0,
    const float* __restrict__ bih0, const float* __restrict__ bhh0,
    const float* __restrict__ wih1, const float* __restrict__ whh1,
    const float* __restrict__ bih1, const float* __restrict__ bhh1,
    const float* __restrict__ wih2, const float* __restrict__ whh2,
    const float* __restrict__ bih2, const float* __restrict__ bhh2,
    const float* __restrict__ wfc, const float* __restrict__ bfc,
    float* __restrict__ out)
{
    const int tid  = threadIdx.x;
    const int w    = tid >> 6;        // wave 0..11
    const int wl   = w >> 2;          // layer 0..2
    const int wg   = w & 3;           // gate-tile group: units [16wg, 16wg+16)
    const int lane = tid & 63;
    const int nloc = lane & 15;       // unit-local index / B-frag col
    const int kg   = lane >> 4;       // k-group 0..3 ; also sample (C-row 4*kg)
    const int b4   = blockIdx.x * 4;
    const int u    = wg * 16 + nloc;  // this lane's hidden unit

    // LDS: XL 64 KiB + HT 24 KiB = 88 KiB -> 1 block/CU
    __shared__ alignas(16) h16 XL[2 * 32 * 512];   // x: 2 chunk-bufs x 32 t x frag(512)
    __shared__ alignas(16) h16 HT[3 * 4 * 1024];   // h[layer][slot=time&3] frag-tiles

    // ---------------- B fragments for THIS wave's layer ----------------
    // Bc = cross operand (x for L0; h_prev-layer for L1/L2), Bs = self-h operand.
    h16x8 Bc[4][2], Bs[4][2];
    float bias[4];
    #pragma unroll
    for (int g = 0; g < 4; ++g) {
        const int ro = g * 64 + u;                  // original row (i,f,g,o blocks)
        if (wl == 0) {
            Bc[g][0] = loadB(wih0, 22, ro, kg * 8,      22);
            Bc[g][1] = Bc[g][0];                        // unused
            Bs[g][0] = loadB(whh0, 64, ro, kg * 8,      64);
            Bs[g][1] = loadB(whh0, 64, ro, 32 + kg * 8, 64);
            bias[g]  = bih0[ro] + bhh0[ro];
        } else if (wl == 1) {
            Bc[g][0] = loadB(wih1, 64, ro, kg * 8,      64);
            Bc[g][1] = loadB(wih1, 64, ro, 32 + kg * 8, 64);
            Bs[g][0] = loadB(whh1, 64, ro, kg * 8,      64);
            Bs[g][1] = loadB(whh1, 64, ro, 32 + kg * 8, 64);
            bias[g]  = bih1[ro] + bhh1[ro];
        } else {
            Bc[g][0] = loadB(wih2, 64, ro, kg * 8,      64);
            Bc[g][1] = loadB(wih2, 64, ro, 32 + kg * 8, 64);
            Bs[g][0] = loadB(whh2, 64, ro, kg * 8,      64);
            Bs[g][1] = loadB(whh2, 64, ro, 32 + kg * 8, 64);
            bias[g]  = bih2[ro] + bhh2[ro];
        }
    }

    // bias as f32x4 C-operand seeds (named vars: braced lists can't cross the macro)
    f32x4 bz[4];
    #pragma unroll
    for (int g = 0; g < 4; ++g) { bz[g][0] = bias[g]; bz[g][1] = 0.f; bz[g][2] = 0.f; bz[g][3] = 0.f; }

    // ---------------- zero LDS (initial h states & x pad must be 0) -------------
    {
        int* xz = (int*)XL;
        for (int i = tid; i < 2 * 32 * 256; i += NTH) xz[i] = 0;
        int* hz = (int*)HT;
        for (int i = tid; i < 3 * 4 * 512; i += NTH) hz[i] = 0;
    }
    __syncthreads();

    // ---------------- x staging: sample bl -> A-row 4*bl, frag layout ------------
    // frag element (m, k) at (k>>3)*128 + m*8 + (k&7) within a 512-slab per t.
    auto stage_x = [&](int chunk) {
        if (tid < 4 * 22) {
            const int bl = tid / 22, ii = tid - bl * 22;
            const float* src = x + (size_t)(b4 + bl) * (22 * 512) + (size_t)ii * 512
                                 + chunk * 32;
            h16* dst = &XL[(chunk & 1) * (32 * 512) + (ii >> 3) * 128 + (4 * bl) * 8 + (ii & 7)];
            #pragma unroll
            for (int q = 0; q < 8; ++q) {
                const float4 v = ((const float4*)src)[q];
                dst[(q * 4 + 0) * 512] = (h16)v.x;
                dst[(q * 4 + 1) * 512] = (h16)v.y;
                dst[(q * 4 + 2) * 512] = (h16)v.z;
                dst[(q * 4 + 3) * 512] = (h16)v.w;
            }
        }
    };
    stage_x(0);

    // ---------------- per-lane constants ----------------
    const int lo8  = lane * 8;                           // A-frag offset (h16 units)
    const int hoff = (u >> 3) * 128 + kg * 32 + (u & 7); // h-write: row 4*kg, unit u
    h16* const HT0 = HT;
    h16* const HT1 = HT + 4096;
    h16* const HT2 = HT + 8192;

    float cst = 0.f;
    f32x4 zc[4];   // pipelined cross-part (+bias) for the NEXT ew of this wave
    #pragma unroll
    for (int g = 0; g < 4; ++g) zc[g] = bz[g];

    // elementwise: 4 gates in-lane, update c, emit h. 10 trans per call.
    auto ew = [&](const f32x4& zi, const f32x4& zf, const f32x4& zg, const f32x4& zo,
                  h16* hb) {
        const float vi = sigm(zi[0]);
        const float vf = sigm(zf[0]);
        const float vg = 2.f * sigm(2.f * zg[0]) - 1.f;
        const float vo = sigm(zo[0]);
        const float c  = vf * cst + vi * vg;
        cst = c;
        hb[hoff] = (h16)(vo * (2.f * sigm(2.f * c) - 1.f));
    };

    __syncthreads();

    // pre-loop: L0's zc for time 0 = bias + Wx * x(0)
    if (wl == 0) {
        const h16x8 ax = *(const h16x8*)&XL[lo8];
        #pragma unroll
        for (int g = 0; g < 4; ++g) zc[g] = MFMA16(ax, Bc[g][0], zc[g]);
    }

    // ============================ diagonal tick loop ============================
    // L0: ew time t at tick t. L1: time t-2. L2: time t-4. 516 ticks.
    #pragma unroll 1
    for (int t = 0; t < TT + 4; ++t) {
        if (wl == 0) {           // ------------- L0 -------------
            if (t < TT) {
                const h16* hs = HT0 + ((t - 1) & 3) * 1024;   // h0(t-1); t=0 -> slot 3 (zero)
                const h16x8 aSlo = *(const h16x8*)(hs + lo8);
                const h16x8 aShi = *(const h16x8*)(hs + lo8 + 512);
                f32x4 z[4];
                #pragma unroll
                for (int g = 0; g < 4; ++g) {
                    z[g] = MFMA16(aSlo, Bs[g][0], zc[g]);
                    z[g] = MFMA16(aShi, Bs[g][1], z[g]);
                }
                // slack: x-part for time t+1 (executes under ew below)
                if (t + 1 < TT) {
                    const int tp = t + 1;
                    const h16x8 ax = *(const h16x8*)&XL[((tp >> 5) & 1) * (32 * 512)
                                                        + (tp & 31) * 512 + lo8];
                    #pragma unroll
                    for (int g = 0; g < 4; ++g)
                        zc[g] = MFMA16(ax, Bc[g][0], bz[g]);
                }
                ew(z[0], z[1], z[2], z[3], HT0 + (t & 3) * 1024);
            }
            // stage next x chunk mid-window
            if ((t & 31) == 16 && (t >> 5) < 15) stage_x((t >> 5) + 1);
        } else if (wl == 1) {    // ------------- L1 (time t-2) -------------
            const bool doew = (t >= 2 && t < TT + 2);
            f32x4 z[4];
            if (doew) {
                const h16* hs = HT1 + ((t - 3) & 3) * 1024;   // h1(t-3); t=2 -> slot 3 (zero)
                const h16x8 aSlo = *(const h16x8*)(hs + lo8);
                const h16x8 aShi = *(const h16x8*)(hs + lo8 + 512);
                #pragma unroll
                for (int g = 0; g < 4; ++g) {
                    z[g] = MFMA16(aSlo, Bs[g][0], zc[g]);
                    z[g] = MFMA16(aShi, Bs[g][1], z[g]);
                }
            }
            if (t >= 1 && t < TT + 1) {   // slack: cross for time t-1 = Wih1*h0(t-1)
                const h16* hc = HT0 + ((t - 1) & 3) * 1024;
                const h16x8 aClo = *(const h16x8*)(hc + lo8);
                const h16x8 aChi = *(const h16x8*)(hc + lo8 + 512);
                #pragma unroll
                for (int g = 0; g < 4; ++g) {
                    zc[g] = MFMA16(aClo, Bc[g][0], bz[g]);
                    zc[g] = MFMA16(aChi, Bc[g][1], zc[g]);
                }
            }
            if (doew) ew(z[0], z[1], z[2], z[3], HT1 + ((t - 2) & 3) * 1024);
        } else {                 // ------------- L2 (time t-4) -------------
            const bool doew = (t >= 4);
            f32x4 z[4];
            if (doew) {
                const h16* hs = HT2 + ((t - 5) & 3) * 1024;   // h2(t-5); t=4 -> slot 3 (zero)
                const h16x8 aSlo = *(const h16x8*)(hs + lo8);
                const h16x8 aShi = *(const h16x8*)(hs + lo8 + 512);
                #pragma unroll
                for (int g = 0; g < 4; ++g) {
                    z[g] = MFMA16(aSlo, Bs[g][0], zc[g]);
                    z[g] = MFMA16(aShi, Bs[g][1], z[g]);
                }
            }
            if (t >= 3 && t < TT + 3) {   // slack: cross for time t-3 = Wih2*h1(t-3)
                const h16* hc = HT1 + ((t - 3) & 3) * 1024;
                const h16x8 aClo = *(const h16x8*)(hc + lo8);
                const h16x8 aChi = *(const h16x8*)(hc + lo8 + 512);
                #pragma unroll
                for (int g = 0; g < 4; ++g) {
                    zc[g] = MFMA16(aClo, Bc[g][0], bz[g]);
                    zc[g] = MFMA16(aChi, Bc[g][1], zc[g]);
                }
            }
            if (doew) ew(z[0], z[1], z[2], z[3], HT2 + ((t - 4) & 3) * 1024);
        }

        __syncthreads();
    }

    // ---------- FC epilogue: h2(time 511) written at tick 515 -> slot 511&3 = 3 ----
    if (tid < 16) {
        const int ms = tid >> 2, o = tid & 3;
        const h16* h2 = HT2 + 3 * 1024;
        float acc = bfc[o];
        #pragma unroll 1
        for (int uu = 0; uu < 64; ++uu)
            acc += (float)h2[(uu >> 3) * 128 + (4 * ms) * 8 + (uu & 7)] * wfc[o * 64 + uu];
        out[(b4 + ms) * 4 + o] = acc;
    }
}

extern "C" void kernel_launch(void* const* d_in, const int* in_sizes, int n_in,
                              void* d_out, int out_size, void* d_ws, size_t ws_size,
                              hipStream_t stream) {
    const float* x    = (const float*)d_in[0];
    const float* wih0 = (const float*)d_in[1];
    const float* whh0 = (const float*)d_in[2];
    const float* bih0 = (const float*)d_in[3];
    const float* bhh0 = (const float*)d_in[4];
    const float* wih1 = (const float*)d_in[5];
    const float* whh1 = (const float*)d_in[6];
    const float* bih1 = (const float*)d_in[7];
    const float* bhh1 = (const float*)d_in[8];
    const float* wih2 = (const float*)d_in[9];
    const float* whh2 = (const float*)d_in[10];
    const float* bih2 = (const float*)d_in[11];
    const float* bhh2 = (const float*)d_in[12];
    const float* wfc  = (const float*)d_in[13];
    const float* bfc  = (const float*)d_in[14];
    float* out = (float*)d_out;

    lstm_mfma<<<dim3(NBLK), dim3(NTH), 0, stream>>>(
        x, wih0, whh0, bih0, bhh0, wih1, whh1, bih1, bhh1,
        wih2, whh2, bih2, bhh2, wfc, bfc, out);
}